// Round 2
// baseline (147.904 us; speedup 1.0000x reference)
//
#include <hip/hip_runtime.h>

#define N_COARSE 200000
#define D 128

// One output row = 128 floats = 512 B. 32 lanes per row, one float4 each:
// gathered read and streaming write are both fully coalesced (32 x 16 B).
// NOTE: harness delivers integer inputs as int32 (NOT the reference's int64).
__global__ void nearest_upsample_gather(const float* __restrict__ x,
                                        const int* __restrict__ idx,
                                        float* __restrict__ out,
                                        int M) {
    int gid = blockIdx.x * blockDim.x + threadIdx.x;
    int total = M * (D / 4);            // one thread per float4
    if (gid >= total) return;

    int m = gid >> 5;                   // row index (D/4 == 32)
    int c = gid & 31;                   // float4 slot within row

    int j = idx[m];                     // same addr across the 32 lanes of a row -> broadcast

    float4 v;
    if ((unsigned)j < (unsigned)N_COARSE) {
        v = reinterpret_cast<const float4*>(x)[(long long)j * (D / 4) + c];
    } else {
        v = make_float4(0.f, 0.f, 0.f, 0.f);   // shadow zero row (j == N_COARSE)
    }
    reinterpret_cast<float4*>(out)[(long long)m * (D / 4) + c] = v;
}

extern "C" void kernel_launch(void* const* d_in, const int* in_sizes, int n_in,
                              void* d_out, int out_size, void* d_ws, size_t ws_size,
                              hipStream_t stream) {
    const float* x = (const float*)d_in[0];
    const int* idx = (const int*)d_in[1];
    float* out = (float*)d_out;

    int M = in_sizes[1];                // upsamples is [M, 1] -> M elements
    int total = M * (D / 4);
    int block = 256;
    int grid = (total + block - 1) / block;

    nearest_upsample_gather<<<grid, block, 0, stream>>>(x, idx, out, M);
}

// Round 4
// 121.884 us; speedup vs baseline: 1.2135x; 1.2135x over previous
//
#include <hip/hip_runtime.h>

#define N_COARSE 200000
#define D 128
#define RPT 4   // rows per thread

typedef float v4f __attribute__((ext_vector_type(4)));
typedef int   v4i __attribute__((ext_vector_type(4)));

// 32 lanes per row, one 16B chunk/lane/row. Each thread covers RPT consecutive
// rows at the same slot: 1x int4 idx load + 4 independent gathers in flight
// (MLP=4). Shadow row (j==N_COARSE) handled by clamp+select so the gather
// loads stay unconditional. Nontemporal stores keep x L2/L3-resident.
__global__ void nearest_upsample_gather4(const float* __restrict__ x,
                                         const int* __restrict__ idx,
                                         float* __restrict__ out,
                                         int M) {
    int gid = blockIdx.x * blockDim.x + threadIdx.x;
    int Mg = (M + RPT - 1) / RPT;       // row groups
    int total = Mg * 32;
    if (gid >= total) return;

    int g = gid >> 5;                   // row group
    int c = gid & 31;                   // 16B slot within row

    const v4f* x4 = reinterpret_cast<const v4f*>(x);
    v4f* o4 = reinterpret_cast<v4f*>(out);
    const v4f zero = (v4f)(0.f);

    int r0 = g * RPT;

    if (r0 + RPT <= M) {
        // fast path: one int4 load covers the 4 row indices (broadcast in-wave)
        v4i j4 = reinterpret_cast<const v4i*>(idx)[g];

        unsigned u0 = (unsigned)j4.x, u1 = (unsigned)j4.y,
                 u2 = (unsigned)j4.z, u3 = (unsigned)j4.w;
        // clamp so shadow index N_COARSE stays in-bounds; select zero after
        unsigned k0 = u0 < N_COARSE ? u0 : (N_COARSE - 1);
        unsigned k1 = u1 < N_COARSE ? u1 : (N_COARSE - 1);
        unsigned k2 = u2 < N_COARSE ? u2 : (N_COARSE - 1);
        unsigned k3 = u3 < N_COARSE ? u3 : (N_COARSE - 1);

        // 4 independent gathers issue back-to-back
        v4f v0 = x4[(size_t)k0 * 32 + c];
        v4f v1 = x4[(size_t)k1 * 32 + c];
        v4f v2 = x4[(size_t)k2 * 32 + c];
        v4f v3 = x4[(size_t)k3 * 32 + c];

        if (u0 >= N_COARSE) v0 = zero;
        if (u1 >= N_COARSE) v1 = zero;
        if (u2 >= N_COARSE) v2 = zero;
        if (u3 >= N_COARSE) v3 = zero;

        size_t ob = (size_t)r0 * 32 + c;
        __builtin_nontemporal_store(v0, o4 + ob);
        __builtin_nontemporal_store(v1, o4 + ob + 32);
        __builtin_nontemporal_store(v2, o4 + ob + 64);
        __builtin_nontemporal_store(v3, o4 + ob + 96);
    } else {
        // tail: per-row scalar path
        for (int k = 0; k < RPT; ++k) {
            int r = r0 + k;
            if (r >= M) break;
            unsigned u = (unsigned)idx[r];
            unsigned kk = u < N_COARSE ? u : (N_COARSE - 1);
            v4f v = x4[(size_t)kk * 32 + c];
            if (u >= N_COARSE) v = zero;
            __builtin_nontemporal_store(v, o4 + (size_t)r * 32 + c);
        }
    }
}

extern "C" void kernel_launch(void* const* d_in, const int* in_sizes, int n_in,
                              void* d_out, int out_size, void* d_ws, size_t ws_size,
                              hipStream_t stream) {
    const float* x = (const float*)d_in[0];
    const int* idx = (const int*)d_in[1];
    float* out = (float*)d_out;

    int M = in_sizes[1];                // upsamples is [M, 1] -> M elements
    int Mg = (M + RPT - 1) / RPT;
    int total = Mg * 32;
    int block = 256;
    int grid = (total + block - 1) / block;

    nearest_upsample_gather4<<<grid, block, 0, stream>>>(x, idx, out, M);
}

// Round 5
// 118.028 us; speedup vs baseline: 1.2531x; 1.0327x over previous
//
#include <hip/hip_runtime.h>

#define N_COARSE 200000
#define D 128
#define RPT 8   // rows per thread

typedef float v4f __attribute__((ext_vector_type(4)));
typedef int   v4i __attribute__((ext_vector_type(4)));

// 32 lanes per row, one 16B chunk/lane/row. Each thread covers RPT consecutive
// rows at the same slot: 2x int4 idx loads + 8 independent gathers in flight
// (MLP=8). Shadow row (j==N_COARSE) handled by clamp+select so the gather
// loads stay unconditional. Nontemporal stores keep x L2/L3-resident;
// nontemporal idx loads keep the read-once index stream out of L2.
__global__ void nearest_upsample_gather8(const float* __restrict__ x,
                                         const int* __restrict__ idx,
                                         float* __restrict__ out,
                                         int M) {
    int gid = blockIdx.x * blockDim.x + threadIdx.x;
    int Mg = (M + RPT - 1) / RPT;       // row groups
    int total = Mg * 32;
    if (gid >= total) return;

    int g = gid >> 5;                   // row group
    int c = gid & 31;                   // 16B slot within row

    const v4f* x4 = reinterpret_cast<const v4f*>(x);
    v4f* o4 = reinterpret_cast<v4f*>(out);
    const v4f zero = (v4f)(0.f);

    int r0 = g * RPT;

    if (r0 + RPT <= M) {
        // two int4 loads cover the 8 row indices (broadcast in-wave)
        const v4i* idx4 = reinterpret_cast<const v4i*>(idx);
        v4i jA = __builtin_nontemporal_load(idx4 + g * 2);
        v4i jB = __builtin_nontemporal_load(idx4 + g * 2 + 1);

        unsigned u[RPT] = {(unsigned)jA.x, (unsigned)jA.y, (unsigned)jA.z, (unsigned)jA.w,
                           (unsigned)jB.x, (unsigned)jB.y, (unsigned)jB.z, (unsigned)jB.w};

        v4f v[RPT];
#pragma unroll
        for (int k = 0; k < RPT; ++k) {
            unsigned kk = u[k] < N_COARSE ? u[k] : (N_COARSE - 1);
            v[k] = x4[(size_t)kk * 32 + c];     // 8 independent gathers in flight
        }
#pragma unroll
        for (int k = 0; k < RPT; ++k) {
            if (u[k] >= N_COARSE) v[k] = zero;  // shadow zero row
        }

        size_t ob = (size_t)r0 * 32 + c;
#pragma unroll
        for (int k = 0; k < RPT; ++k) {
            __builtin_nontemporal_store(v[k], o4 + ob + (size_t)k * 32);
        }
    } else {
        // tail: per-row scalar path
        for (int k = 0; k < RPT; ++k) {
            int r = r0 + k;
            if (r >= M) break;
            unsigned uu = (unsigned)idx[r];
            unsigned kk = uu < N_COARSE ? uu : (N_COARSE - 1);
            v4f v = x4[(size_t)kk * 32 + c];
            if (uu >= N_COARSE) v = zero;
            __builtin_nontemporal_store(v, o4 + (size_t)r * 32 + c);
        }
    }
}

extern "C" void kernel_launch(void* const* d_in, const int* in_sizes, int n_in,
                              void* d_out, int out_size, void* d_ws, size_t ws_size,
                              hipStream_t stream) {
    const float* x = (const float*)d_in[0];
    const int* idx = (const int*)d_in[1];
    float* out = (float*)d_out;

    int M = in_sizes[1];                // upsamples is [M, 1] -> M elements
    int Mg = (M + RPT - 1) / RPT;
    int total = Mg * 32;
    int block = 256;
    int grid = (total + block - 1) / block;

    nearest_upsample_gather8<<<grid, block, 0, stream>>>(x, idx, out, M);
}